// Round 10
// baseline (307.993 us; speedup 1.0000x reference)
//
#include <hip/hip_runtime.h>

// Problem constants (B,C,H,W)=(32,64,64,64), code_size=512
#define HWDIM 4096
#define CDIM  64
#define KDIM  512
#define ST_ELEMS   8388608   // 32*64*64*64
#define LOSS_OFF   8519680   // ST_ELEMS + 32*64*64

// R15 = R14 with the pragma-placement fix (clang: '#pragma clang fp' must
// open a compound statement).
// R14: MFMA bf16 prune + sound exact rescan.
//  - Distance pass on the MATRIX pipe: v_mfma_f32_32x32x16_bf16, A=codebook
//    (M=codes), B=x (N=px), D[code][px]=dot. 64 MFMA/wave for 32px*512codes.
//  - Layout hedge: channel->(lane-half,elem) assignment uses ONE function
//    (chOf) on BOTH operands (A pre-swizzled in ws, B packed from regs).
//    A and B share the lane->k map on CDNA, so ANY consistent permutation
//    gives the identical dot. Trusted deps: row/col=lane&31, C/D map
//    col=lane&31,row=(reg&3)+8*(reg>>2)+4*(lane>>5) (HW-verified m74/m101).
//  - Soundness: RNE-bf16 both sides -> |f~-f| <= 2A+2eps ~ 6e-3
//    (||c||<=0.016, ||x||max<=~12). MARGIN=0.008 -> true argmin always
//    collected. Rescan recomputes R8's bit-identical fmaf chain + e-formula;
//    packed-u64 min reproduces first-minimum tie-break exactly.
//  - Geometry: 1024 blocks x 256 thr (4 waves x 32 px); px held by a lane
//    pair (hi=0/1) scanning disjoint 256-code halves; shfl_xor(32) merge.
//    Exact S via split-channel partials + 4-shfl exchange (t_i = P_i + Q_i,
//    fp add commutes -> both lanes bit-identical). No waves_per_eu.

#define MRG 0.008f

typedef unsigned int uint;
typedef short short8 __attribute__((ext_vector_type(8)));
typedef float f32x16 __attribute__((ext_vector_type(16)));

// numpy fp32 pairwise sum-of-squares of 64 contiguous values — bit-validated.
__device__ __forceinline__ float np_sumsq64(const float a[64]) {
#pragma clang fp contract(off)
  float v[16];
#pragma unroll
  for (int i = 0; i < 16; ++i) {
    float s0 = a[i]      * a[i];
    float s1 = a[i + 16] * a[i + 16];
    float s2 = a[i + 32] * a[i + 32];
    float s3 = a[i + 48] * a[i + 48];
    v[i] = (s0 + s1) + (s2 + s3);
  }
  float t0 = (v[0] + v[8])  + (v[4] + v[12]);
  float t1 = (v[1] + v[9])  + (v[5] + v[13]);
  float t2 = (v[2] + v[10]) + (v[6] + v[14]);
  float t3 = (v[3] + v[11]) + (v[7] + v[15]);
  return (t0 + t2) + (t1 + t3);
}

// fp32 -> bf16 with round-to-nearest-even (bits form).
__device__ __forceinline__ uint bf16rne(float f) {
  uint u = __builtin_bit_cast(uint, f);
  return (u + 0x7FFFu + ((u >> 16) & 1u)) >> 16;
}

// Channel owned by slot m (0..31) on lane-half hi: koff=m>>3, j=m&7;
// ch = koff*16 + 4*hi + j (+4 if j>=4). Used identically for A and B packing
// (consistent channel placement on both operands => identical dot).
__device__ __forceinline__ int chOf(int m, int hi) {
  const int j = m & 7;
  return ((m >> 3) << 4) + (hi << 2) + j + ((j >= 4) ? 4 : 0);
}

// ---------------- pre-kernel: sc[512] + swizzled bf16 codebook into ws -----
// ws layout: [0..511] sc (f32 bits); ws+512: A-fragments, u32 index
// ((ct*4+koff)*64 + lane)*4 + r  (r = elem pair 2r,2r+1), 64 KB.
__global__ void vq_pre(const float* __restrict__ cb, uint* __restrict__ ws) {
  const int g = blockIdx.x * 256 + threadIdx.x;   // 0..1023
  if (g < KDIM) {
    float row[64];
#pragma unroll
    for (int c = 0; c < 64; ++c) row[c] = cb[(g << 6) + c];
    ((float*)ws)[g] = np_sumsq64(row);
  }
  const int ct = g >> 6, lane = g & 63;
  const int hi = lane >> 5;
  const int code = (ct << 5) + (lane & 31);
  const float* cr = cb + ((size_t)code << 6);
#pragma unroll
  for (int koff = 0; koff < 4; ++koff) {
    uint* dst = ws + 512 + (((ct * 4 + koff) * 64 + lane) << 2);
#pragma unroll
    for (int r = 0; r < 4; ++r) {
      const int m0 = koff * 8 + 2 * r;
      dst[r] = bf16rne(cr[chOf(m0, hi)]) |
               (bf16rne(cr[chOf(m0 + 1, hi)]) << 16);
    }
  }
}

// ---------------- main kernel ----------------------------------------------
__global__ __launch_bounds__(256)
void vq_kernel(
    const float* __restrict__ x, const float* __restrict__ cb,
    const uint* __restrict__ ws,
    float* __restrict__ st, float* __restrict__ idxo, float* __restrict__ loss)
{
  __shared__ float scL[KDIM];
  __shared__ float lred[4];

  const int tid = threadIdx.x;
  const int l   = tid & 63;          // lane
  const int w   = tid >> 6;          // wave in block
  const int hi  = l >> 5;            // code-half of the px lane-pair
  const int b   = blockIdx.x & 31;
  const int px  = ((blockIdx.x >> 5) << 7) + (w << 5) + (l & 31);

  scL[tid]       = ((const float*)ws)[tid];
  scL[tid + 256] = ((const float*)ws)[tid + 256];

  // Own 32 fp32 channels (chOf map), coalesced: lanes 0-31 same ch set,
  // consecutive px (128B segments); lanes 32-63 the complementary set.
  const float* xb = x + (size_t)b * (CDIM * HWDIM) + px;
  float o[32];
#pragma unroll
  for (int m = 0; m < 32; ++m) o[m] = xb[chOf(m, hi) * HWDIM];

  // Exact S: np tree split across the lane pair. hi=0 owns v[0..3],v[8..11];
  // hi=1 owns v[4..7],v[12..15]. t_i = P_i + Q_i with P from hi0, Q from hi1;
  // fp add commutes bitwise -> both lanes compute identical S.
  float S, pp0, pp1, pp2, pp3;
  {
#pragma clang fp contract(off)
    float vA0 = (o[0]*o[0] + o[8]*o[8])   + (o[16]*o[16] + o[24]*o[24]);
    float vA1 = (o[1]*o[1] + o[9]*o[9])   + (o[17]*o[17] + o[25]*o[25]);
    float vA2 = (o[2]*o[2] + o[10]*o[10]) + (o[18]*o[18] + o[26]*o[26]);
    float vA3 = (o[3]*o[3] + o[11]*o[11]) + (o[19]*o[19] + o[27]*o[27]);
    float vB0 = (o[4]*o[4] + o[12]*o[12]) + (o[20]*o[20] + o[28]*o[28]);
    float vB1 = (o[5]*o[5] + o[13]*o[13]) + (o[21]*o[21] + o[29]*o[29]);
    float vB2 = (o[6]*o[6] + o[14]*o[14]) + (o[22]*o[22] + o[30]*o[30]);
    float vB3 = (o[7]*o[7] + o[15]*o[15]) + (o[23]*o[23] + o[31]*o[31]);
    pp0 = vA0 + vB0; pp1 = vA1 + vB1; pp2 = vA2 + vB2; pp3 = vA3 + vB3;
  }
  {
    float qq0 = __shfl_xor(pp0, 32), qq1 = __shfl_xor(pp1, 32);
    float qq2 = __shfl_xor(pp2, 32), qq3 = __shfl_xor(pp3, 32);
    {
#pragma clang fp contract(off)
      float t0 = pp0 + qq0, t1 = pp1 + qq1, t2 = pp2 + qq2, t3 = pp3 + qq3;
      S = (t0 + t2) + (t1 + t3);
    }
  }

  // B fragments: bf16-RNE of own channels, elem j = o[koff*8+j].
  short8 bfr[4];
#pragma unroll
  for (int koff = 0; koff < 4; ++koff) {
    uint4 bu;
    bu.x = bf16rne(o[koff*8+0]) | (bf16rne(o[koff*8+1]) << 16);
    bu.y = bf16rne(o[koff*8+2]) | (bf16rne(o[koff*8+3]) << 16);
    bu.z = bf16rne(o[koff*8+4]) | (bf16rne(o[koff*8+5]) << 16);
    bu.w = bf16rne(o[koff*8+6]) | (bf16rne(o[koff*8+7]) << 16);
    bfr[koff] = __builtin_bit_cast(short8, bu);
  }
  __syncthreads();

  // ---- MFMA prune pass: 16 code-tiles x 4 K-steps. Lane sees, per tile,
  // 16 codes (C/D rows (r&3)+8*(r>>2)+4*hi) for its px (col l&31).
  float runm = __builtin_inff();
  uint msk[8] = {0u,0u,0u,0u,0u,0u,0u,0u};
  const short8* wsA = reinterpret_cast<const short8*>(ws + 512);
#pragma unroll
  for (int ct = 0; ct < 16; ++ct) {
    short8 a0 = wsA[(ct*4 + 0)*64 + l];
    short8 a1 = wsA[(ct*4 + 1)*64 + l];
    short8 a2 = wsA[(ct*4 + 2)*64 + l];
    short8 a3 = wsA[(ct*4 + 3)*64 + l];
    f32x16 acc = {0.f,0.f,0.f,0.f,0.f,0.f,0.f,0.f,
                  0.f,0.f,0.f,0.f,0.f,0.f,0.f,0.f};
    acc = __builtin_amdgcn_mfma_f32_32x32x16_bf16(a0, bfr[0], acc, 0, 0, 0);
    acc = __builtin_amdgcn_mfma_f32_32x32x16_bf16(a1, bfr[1], acc, 0, 0, 0);
    acc = __builtin_amdgcn_mfma_f32_32x32x16_bf16(a2, bfr[2], acc, 0, 0, 0);
    acc = __builtin_amdgcn_mfma_f32_32x32x16_bf16(a3, bfr[3], acc, 0, 0, 0);
    float fv[16];
    float mn = runm;
#pragma unroll
    for (int r = 0; r < 16; ++r) {
      const int code = (ct << 5) + (r & 3) + ((r >> 2) << 3) + (hi << 2);
      fv[r] = __builtin_fmaf(-2.0f, acc[r], scL[code]);   // f~ = sc - 2*dot
      mn = fminf(mn, fv[r]);
    }
    runm = mn;
    const float th = mn + MRG;   // includes current tile's min — still sound
    uint bits = 0u;
#pragma unroll
    for (int r = 0; r < 16; ++r) bits |= (fv[r] < th) ? (1u << r) : 0u;
    msk[ct >> 1] |= bits << ((ct & 1) << 4);
  }

  // ---- Assemble full 64-ch fp32 x per lane (pair exchange + select).
  float rc[32];
#pragma unroll
  for (int m = 0; m < 32; ++m) rc[m] = __shfl_xor(o[m], 32);
  const bool h0 = (hi == 0);
  float xe[32], xo[32];   // xe: even ch-quads (ch 8g+pos), xo: odd (8g+4+pos)
#pragma unroll
  for (int m = 0; m < 32; ++m) {
    xe[m] = h0 ? o[m] : rc[m];
    xo[m] = h0 ? rc[m] : o[m];
  }

  // ---- Exact rescan (bit-identical R8 fmaf chain, ascending channel).
#define FQ4(RR, X0, X1, X2, X3) \
    d = __builtin_fmaf(X0, RR.x, d); d = __builtin_fmaf(X1, RR.y, d); \
    d = __builtin_fmaf(X2, RR.z, d); d = __builtin_fmaf(X3, RR.w, d);
#define RESROW(rw) { float4 rr; \
    rr = rw[0];  FQ4(rr, xe[0],  xe[1],  xe[2],  xe[3])  \
    rr = rw[1];  FQ4(rr, xo[0],  xo[1],  xo[2],  xo[3])  \
    rr = rw[2];  FQ4(rr, xe[4],  xe[5],  xe[6],  xe[7])  \
    rr = rw[3];  FQ4(rr, xo[4],  xo[5],  xo[6],  xo[7])  \
    rr = rw[4];  FQ4(rr, xe[8],  xe[9],  xe[10], xe[11]) \
    rr = rw[5];  FQ4(rr, xo[8],  xo[9],  xo[10], xo[11]) \
    rr = rw[6];  FQ4(rr, xe[12], xe[13], xe[14], xe[15]) \
    rr = rw[7];  FQ4(rr, xo[12], xo[13], xo[14], xo[15]) \
    rr = rw[8];  FQ4(rr, xe[16], xe[17], xe[18], xe[19]) \
    rr = rw[9];  FQ4(rr, xo[16], xo[17], xo[18], xo[19]) \
    rr = rw[10]; FQ4(rr, xe[20], xe[21], xe[22], xe[23]) \
    rr = rw[11]; FQ4(rr, xo[20], xo[21], xo[22], xo[23]) \
    rr = rw[12]; FQ4(rr, xe[24], xe[25], xe[26], xe[27]) \
    rr = rw[13]; FQ4(rr, xo[24], xo[25], xo[26], xo[27]) \
    rr = rw[14]; FQ4(rr, xe[28], xe[29], xe[30], xe[31]) \
    rr = rw[15]; FQ4(rr, xo[28], xo[29], xo[30], xo[31]) }

  unsigned long long pk = ~0ull;
  const float* scg = (const float*)ws;
#pragma unroll
  for (int wd = 0; wd < 8; ++wd) {
    uint m_ = msk[wd];
    while (__any(m_ != 0u)) {
      if (m_ != 0u) {
        const int t   = __ffs(m_) - 1;
        const int ctv = (wd << 1) + (t >> 4);
        const int r   = t & 15;
        const int kk  = (ctv << 5) + (r & 3) + ((r >> 2) << 3) + (hi << 2);
        const float4* rw = (const float4*)(cb + ((size_t)kk << 6));
        float d = 0.f;
        RESROW(rw)
        float e;
        { _Pragma("clang fp contract(off)") e = (S - (d + d)) + scg[kk]; }
        unsigned long long c_ =
            ((unsigned long long)__float_as_uint(e) << 32) | (uint)kk;
        if (c_ < pk) pk = c_;
        m_ &= m_ - 1u;
      }
    }
  }
#undef RESROW
#undef FQ4

  // Merge the lane pair (disjoint code halves): u64 min == first-min exact.
  { unsigned long long o_ = __shfl_xor(pk, 32); if (o_ < pk) pk = o_; }
  const int besti = (int)(pk & 0xffffffffu);

  // ---- Epilogue (hi=0 lanes only; full 64-ch, R8-identical chains).
  float lsum = 0.f;
  if (h0) {
    const float* crow = cb + ((size_t)besti << 6);
    float* stp = st + (size_t)b * (CDIM * HWDIM) + px;
#pragma unroll
    for (int q = 0; q < 16; ++q) {
#pragma unroll
      for (int pos = 0; pos < 4; ++pos) {
        const int c = q * 4 + pos;
        const float xv = (q & 1) ? xo[(q >> 1) * 4 + pos]
                                 : xe[(q >> 1) * 4 + pos];
        const float cv = crow[c];
        float df;
        { _Pragma("clang fp contract(off)") df = cv - xv; }
        lsum = __builtin_fmaf(df, df, lsum);
        stp[c * HWDIM] = cv;
      }
    }
    idxo[b * HWDIM + px] = (float)besti;
  }

  // Block reduce loss, one atomic per block (hi=1 lanes contribute exact 0).
#pragma unroll
  for (int off = 32; off > 0; off >>= 1) lsum += __shfl_down(lsum, off);
  if ((tid & 63) == 0) lred[tid >> 6] = lsum;
  __syncthreads();
  if (tid == 0) {
    float t = (lred[0] + lred[1]) + (lred[2] + lred[3]);
    atomicAdd(loss, t * (1.25f / 8388608.f));
  }
}

extern "C" void kernel_launch(void* const* d_in, const int* in_sizes, int n_in,
                              void* d_out, int out_size, void* d_ws, size_t ws_size,
                              hipStream_t stream) {
  const float* x  = (const float*)d_in[0];   // (32,64,64,64) fp32
  const float* cb = (const float*)d_in[1];   // (512,64) fp32
  float* st   = (float*)d_out;               // (32,64,64,64)
  float* idxo = (float*)d_out + ST_ELEMS;    // (32,64,64) as float
  float* loss = (float*)d_out + LOSS_OFF;    // scalar
  uint*  ws   = (uint*)d_ws;                 // 2KB sc + 64KB swizzled bf16 cb

  (void)hipMemsetAsync(loss, 0, sizeof(float), stream);  // d_out poisoned/call
  vq_pre<<<dim3(4), dim3(256), 0, stream>>>(cb, ws);
  vq_kernel<<<dim3(1024), dim3(256), 0, stream>>>(x, cb, ws, st, idxo, loss);
}

// Round 11
// 260.449 us; speedup vs baseline: 1.1825x; 1.1825x over previous
//
#include <hip/hip_runtime.h>

// Problem constants (B,C,H,W)=(32,64,64,64), code_size=512
#define HWDIM 4096
#define CDIM  64
#define KDIM  512
#define ST_ELEMS   8388608   // 32*64*64*64
#define LOSS_OFF   8519680   // ST_ELEMS + 32*64*64

// R16: R15's validated MFMA-prune + exact-rescan, restructured to kill the
// spill (R15: 128-float pair-exchange live set -> VGPR 256 + 112MB scratch,
// occupancy 1 wave/SIMD).
//  - Each lane loads the FULL 64 fp32 channels of its px (lanes l and l+32
//    duplicate the same px; cache-served). No pair exchange, no xe/xo.
//  - B fragment takes the lane's 32 hi-matching channels via 64 static-index
//    cndmask selects (no dynamic indexing -> no scratch).
//  - Channel->slot map ch = koff*16 + hi*8 + j applied identically in the
//    pre-kernel (A side) and the B pack — R15 PROVED any consistent map
//    yields the exact dot (sum over ch is permutation-invariant).
//  - C/D map (row=(r&3)+8*(r>>2)+4*hi, col=lane&31), MARGIN=0.008 soundness,
//    prune masks, u64 first-min tie-break, R8-bit-identical rescan chain,
//    S/sc np trees, epilogue chains: all byte-identical logic to R15 (which
//    passed with absmax 7.629395e-06).
//  - Live set ~150 regs (o64 + bfr16 + msk8 + transients) -> no spill.

#define MRG 0.008f

typedef unsigned int uint;
typedef short short8 __attribute__((ext_vector_type(8)));
typedef float f32x16 __attribute__((ext_vector_type(16)));

// numpy fp32 pairwise sum-of-squares of 64 contiguous values — bit-validated.
__device__ __forceinline__ float np_sumsq64(const float a[64]) {
#pragma clang fp contract(off)
  float v[16];
#pragma unroll
  for (int i = 0; i < 16; ++i) {
    float s0 = a[i]      * a[i];
    float s1 = a[i + 16] * a[i + 16];
    float s2 = a[i + 32] * a[i + 32];
    float s3 = a[i + 48] * a[i + 48];
    v[i] = (s0 + s1) + (s2 + s3);
  }
  float t0 = (v[0] + v[8])  + (v[4] + v[12]);
  float t1 = (v[1] + v[9])  + (v[5] + v[13]);
  float t2 = (v[2] + v[10]) + (v[6] + v[14]);
  float t3 = (v[3] + v[11]) + (v[7] + v[15]);
  return (t0 + t2) + (t1 + t3);
}

// fp32 -> bf16 with round-to-nearest-even (bits form).
__device__ __forceinline__ uint bf16rne(float f) {
  uint u = __builtin_bit_cast(uint, f);
  return (u + 0x7FFFu + ((u >> 16) & 1u)) >> 16;
}

// ---------------- pre-kernel: sc[512] + swizzled bf16 codebook into ws -----
// ws: [0..511] sc (f32); ws+512: A-frags, u32 idx ((ct*4+koff)*64+lane)*4+r,
// slot (lane,koff,j): ch = koff*16 + (lane>>5)*8 + j. 64 KB.
__global__ void vq_pre(const float* __restrict__ cb, uint* __restrict__ ws) {
  const int g = blockIdx.x * 256 + threadIdx.x;   // 0..1023
  if (g < KDIM) {
    float row[64];
#pragma unroll
    for (int c = 0; c < 64; ++c) row[c] = cb[(g << 6) + c];
    ((float*)ws)[g] = np_sumsq64(row);
  }
  const int ct = g >> 6, lane = g & 63;
  const int hi = lane >> 5;
  const int code = (ct << 5) + (lane & 31);
  const float* cr = cb + ((size_t)code << 6);
#pragma unroll
  for (int koff = 0; koff < 4; ++koff) {
    uint* dst = ws + 512 + (((ct * 4 + koff) * 64 + lane) << 2);
#pragma unroll
    for (int r = 0; r < 4; ++r) {
      const int ch = koff * 16 + hi * 8 + 2 * r;
      dst[r] = bf16rne(cr[ch]) | (bf16rne(cr[ch + 1]) << 16);
    }
  }
}

// ---------------- main kernel ----------------------------------------------
__global__ __launch_bounds__(256)
void vq_kernel(
    const float* __restrict__ x, const float* __restrict__ cb,
    const uint* __restrict__ ws,
    float* __restrict__ st, float* __restrict__ idxo, float* __restrict__ loss)
{
  __shared__ float scL[KDIM];
  __shared__ float lred[4];

  const int tid = threadIdx.x;
  const int l   = tid & 63;          // lane
  const int w   = tid >> 6;          // wave in block
  const int hi  = l >> 5;            // B-fragment k-half of this lane
  const int b   = blockIdx.x & 31;
  const int px  = ((blockIdx.x >> 5) << 7) + (w << 5) + (l & 31);

  scL[tid]       = ((const float*)ws)[tid];
  scL[tid + 256] = ((const float*)ws)[tid + 256];

  // Full 64-channel fp32 x for this lane's px (lanes l, l+32 duplicate).
  const float* xb = x + (size_t)b * (CDIM * HWDIM) + px;
  float o[64];
#pragma unroll
  for (int m = 0; m < 64; ++m) o[m] = xb[m * HWDIM];
#pragma unroll
  for (int m = 0; m < 64; ++m) asm("" : "+v"(o[m]));

  // Exact S — R8's bit-identical numpy pairwise tree (all channels local).
  float S;
  {
#pragma clang fp contract(off)
#define SQV(I) float v##I = (o[I]*o[I] + o[I+16]*o[I+16]) \
                          + (o[I+32]*o[I+32] + o[I+48]*o[I+48]);
    SQV(0) SQV(1) SQV(2) SQV(3) SQV(4) SQV(5) SQV(6) SQV(7)
    SQV(8) SQV(9) SQV(10) SQV(11) SQV(12) SQV(13) SQV(14) SQV(15)
#undef SQV
    float t0 = (v0 + v8)  + (v4 + v12);
    float t1 = (v1 + v9)  + (v5 + v13);
    float t2 = (v2 + v10) + (v6 + v14);
    float t3 = (v3 + v11) + (v7 + v15);
    S = (t0 + t2) + (t1 + t3);
  }

  // B fragments: lane supplies ch = koff*16 + hi*8 + j (static-index selects).
  short8 bfr[4];
#define BPACK(K) { \
    float s0 = hi ? o[(K)*16+ 8] : o[(K)*16+ 0]; \
    float s1 = hi ? o[(K)*16+ 9] : o[(K)*16+ 1]; \
    float s2 = hi ? o[(K)*16+10] : o[(K)*16+ 2]; \
    float s3 = hi ? o[(K)*16+11] : o[(K)*16+ 3]; \
    float s4 = hi ? o[(K)*16+12] : o[(K)*16+ 4]; \
    float s5 = hi ? o[(K)*16+13] : o[(K)*16+ 5]; \
    float s6 = hi ? o[(K)*16+14] : o[(K)*16+ 6]; \
    float s7 = hi ? o[(K)*16+15] : o[(K)*16+ 7]; \
    uint4 bu; \
    bu.x = bf16rne(s0) | (bf16rne(s1) << 16); \
    bu.y = bf16rne(s2) | (bf16rne(s3) << 16); \
    bu.z = bf16rne(s4) | (bf16rne(s5) << 16); \
    bu.w = bf16rne(s6) | (bf16rne(s7) << 16); \
    bfr[K] = __builtin_bit_cast(short8, bu); }
  BPACK(0) BPACK(1) BPACK(2) BPACK(3)
#undef BPACK
  __syncthreads();

  // ---- MFMA prune pass (R15-validated): 16 code-tiles x 4 K-steps.
  // Lane sees 16 codes/tile (rows (r&3)+8*(r>>2)+4*hi) for its px (col l&31).
  float runm = __builtin_inff();
  uint msk[8] = {0u,0u,0u,0u,0u,0u,0u,0u};
  const short8* wsA = reinterpret_cast<const short8*>(ws + 512);
#pragma unroll
  for (int ct = 0; ct < 16; ++ct) {
    short8 a0 = wsA[(ct*4 + 0)*64 + l];
    short8 a1 = wsA[(ct*4 + 1)*64 + l];
    short8 a2 = wsA[(ct*4 + 2)*64 + l];
    short8 a3 = wsA[(ct*4 + 3)*64 + l];
    f32x16 acc = {0.f,0.f,0.f,0.f,0.f,0.f,0.f,0.f,
                  0.f,0.f,0.f,0.f,0.f,0.f,0.f,0.f};
    acc = __builtin_amdgcn_mfma_f32_32x32x16_bf16(a0, bfr[0], acc, 0, 0, 0);
    acc = __builtin_amdgcn_mfma_f32_32x32x16_bf16(a1, bfr[1], acc, 0, 0, 0);
    acc = __builtin_amdgcn_mfma_f32_32x32x16_bf16(a2, bfr[2], acc, 0, 0, 0);
    acc = __builtin_amdgcn_mfma_f32_32x32x16_bf16(a3, bfr[3], acc, 0, 0, 0);
    float fv[16];
    float mn = runm;
#pragma unroll
    for (int r = 0; r < 16; ++r) {
      const int code = (ct << 5) + (r & 3) + ((r >> 2) << 3) + (hi << 2);
      fv[r] = __builtin_fmaf(-2.0f, acc[r], scL[code]);   // f~ = sc - 2*dot
      mn = fminf(mn, fv[r]);
    }
    runm = mn;
    const float th = mn + MRG;   // includes current tile's min — still sound
    uint bits = 0u;
#pragma unroll
    for (int r = 0; r < 16; ++r) bits |= (fv[r] < th) ? (1u << r) : 0u;
    msk[ct >> 1] |= bits << ((ct & 1) << 4);
  }

  // ---- Exact rescan (R8's bit-identical ascending-channel fmaf chain).
#define RQ(Q) { float4 rr = rw[Q]; \
    d = __builtin_fmaf(o[4*(Q)+0], rr.x, d); \
    d = __builtin_fmaf(o[4*(Q)+1], rr.y, d); \
    d = __builtin_fmaf(o[4*(Q)+2], rr.z, d); \
    d = __builtin_fmaf(o[4*(Q)+3], rr.w, d); }
#define RESROW \
    RQ(0) RQ(1) RQ(2) RQ(3) RQ(4) RQ(5) RQ(6) RQ(7) \
    RQ(8) RQ(9) RQ(10) RQ(11) RQ(12) RQ(13) RQ(14) RQ(15)

  unsigned long long pk = ~0ull;
#pragma unroll
  for (int wd = 0; wd < 8; ++wd) {
    uint m_ = msk[wd];
    while (__any(m_ != 0u)) {
      if (m_ != 0u) {
        const int t   = __ffs(m_) - 1;
        const int ctv = (wd << 1) + (t >> 4);
        const int r   = t & 15;
        const int kk  = (ctv << 5) + (r & 3) + ((r >> 2) << 3) + (hi << 2);
        const float4* rw = (const float4*)(cb + ((size_t)kk << 6));
        float d = 0.f;
        RESROW
        float e;
        { _Pragma("clang fp contract(off)") e = (S - (d + d)) + scL[kk]; }
        unsigned long long c_ =
            ((unsigned long long)__float_as_uint(e) << 32) | (uint)kk;
        if (c_ < pk) pk = c_;
        m_ &= m_ - 1u;
      }
    }
  }
#undef RESROW
#undef RQ

  // Merge the lane pair (disjoint code rows): u64 min == first-min exact.
  { unsigned long long o_ = __shfl_xor(pk, 32); if (o_ < pk) pk = o_; }
  const int besti = (int)(pk & 0xffffffffu);

  // ---- Epilogue (hi=0 lanes; full 64-ch in o[], R8-identical chains).
  float lsum = 0.f;
  if (hi == 0) {
    const float* crow = cb + ((size_t)besti << 6);
    float* stp = st + (size_t)b * (CDIM * HWDIM) + px;
#pragma unroll
    for (int c = 0; c < 64; ++c) {
      const float cv = crow[c];
      float df;
      { _Pragma("clang fp contract(off)") df = cv - o[c]; }
      lsum = __builtin_fmaf(df, df, lsum);
      stp[c * HWDIM] = cv;
    }
    idxo[b * HWDIM + px] = (float)besti;
  }

  // Block reduce loss, one atomic per block (hi=1 lanes contribute exact 0).
#pragma unroll
  for (int off = 32; off > 0; off >>= 1) lsum += __shfl_down(lsum, off);
  if ((tid & 63) == 0) lred[tid >> 6] = lsum;
  __syncthreads();
  if (tid == 0) {
    float t = (lred[0] + lred[1]) + (lred[2] + lred[3]);
    atomicAdd(loss, t * (1.25f / 8388608.f));
  }
}

extern "C" void kernel_launch(void* const* d_in, const int* in_sizes, int n_in,
                              void* d_out, int out_size, void* d_ws, size_t ws_size,
                              hipStream_t stream) {
  const float* x  = (const float*)d_in[0];   // (32,64,64,64) fp32
  const float* cb = (const float*)d_in[1];   // (512,64) fp32
  float* st   = (float*)d_out;               // (32,64,64,64)
  float* idxo = (float*)d_out + ST_ELEMS;    // (32,64,64) as float
  float* loss = (float*)d_out + LOSS_OFF;    // scalar
  uint*  ws   = (uint*)d_ws;                 // 2KB sc + 64KB swizzled bf16 cb

  (void)hipMemsetAsync(loss, 0, sizeof(float), stream);  // d_out poisoned/call
  vq_pre<<<dim3(4), dim3(256), 0, stream>>>(cb, ws);
  vq_kernel<<<dim3(1024), dim3(256), 0, stream>>>(x, cb, ws, st, idxo, loss);
}